// Round 16
// baseline (41.958 us; speedup 1.0000x reference)
//
#include <hip/hip_runtime.h>
#include <hip/hip_bf16.h>

#define B_   16
#define L_   256
#define D_   512
#define C_   8
#define P_   12
#define LOUT 244
#define O_   512
#define GM   3904   // 16*244 rows per channel
#define BM   128
#define BN   256
#define BK   32
#define NMT  31     // ceil(3904/128)
#define NNT  2
#define NSTEP 16    // D_/BK
#define NFIRB 976   // 16 b x 61 lg, one task per block

typedef __attribute__((ext_vector_type(8))) short bf16x8;
typedef __attribute__((ext_vector_type(4))) float f32x4;

__device__ __forceinline__ unsigned short f2bf(float f) {
    unsigned int u = __float_as_uint(f);
    unsigned int r = (u + 0x7FFFu + ((u >> 16) & 1u)) >> 16;
    return (unsigned short)r;
}

__device__ __forceinline__ void async_copy16(const void* g, void* l) {
    __builtin_amdgcn_global_load_lds(
        (const __attribute__((address_space(1))) unsigned int*)g,
        (__attribute__((address_space(3))) unsigned int*)l, 16, 0, 0);
}

// ---------------------------------------------------------------------------
// prep v4: r2 parallelism (976 FIR blocks, 3.8 waves/SIMD) + float4 widths.
//   Block = task (b, lg): 4 rows. Thread = channel-half (cg: 4 channels) x
//   d-quad. 15 float4 loads (dup across cg pair = L1 hit), 4ch x 4rows FIR,
//   ushort4 stores.
//   blocks [976,3024): Ws f32 -> bf16 (one float4 per thread).
// ---------------------------------------------------------------------------
__global__ __launch_bounds__(256) void prep(const float* __restrict__ inp,
                                            const float* __restrict__ Ws,
                                            const float* __restrict__ Wt,
                                            unsigned short* __restrict__ tmp,
                                            unsigned short* __restrict__ wsb) {
    int bid = blockIdx.x;
    int tid = threadIdx.x;

    if (bid >= NFIRB) {                     // ---- Ws convert path ----
        int g = (bid - NFIRB) * 256 + tid;  // 524288 float4s
        float4 v = ((const float4*)Ws)[g];
        ushort4 o;
        o.x = f2bf(v.x); o.y = f2bf(v.y); o.z = f2bf(v.z); o.w = f2bf(v.w);
        ((ushort4*)wsb)[g] = o;
        return;
    }

    // ---- FIR path ----
    __shared__ float wt_s[C_][P_];
    if (tid < C_ * P_) wt_s[tid / P_][tid % P_] = Wt[tid];
    __syncthreads();

    int b = bid / 61, lg = bid % 61;
    int cg = tid >> 7;                  // 0/1 -> channels cg*4 .. cg*4+3
    int dq = tid & 127;                 // d-quad
    int l0 = lg * 4;
    int d0 = dq * 4;

    // window rows l0..l0+14 (l0 <= 240 -> l0+14 = 254 < 256: in-bounds)
    float4 rv[15];
    const float* ibase = inp + ((size_t)b * L_ + l0) * D_ + d0;
#pragma unroll
    for (int j = 0; j < 15; ++j)
        rv[j] = *(const float4*)(ibase + (size_t)j * D_);

#pragma unroll
    for (int cc = 0; cc < 4; ++cc) {
        int c = cg * 4 + cc;
        float w[P_];
#pragma unroll
        for (int p = 0; p < P_; ++p) w[p] = wt_s[c][p];
        unsigned short* ob = tmp + (((size_t)(c * B_ + b)) * LOUT + l0) * D_ + d0;
#pragma unroll
        for (int j = 0; j < 4; ++j) {
            float sx = 0.f, sy = 0.f, sz = 0.f, sw = 0.f;
#pragma unroll
            for (int p = 0; p < P_; ++p) {
                sx += w[p] * rv[j + p].x;
                sy += w[p] * rv[j + p].y;
                sz += w[p] * rv[j + p].z;
                sw += w[p] * rv[j + p].w;
            }
            ushort4 ov;
            ov.x = f2bf(sx); ov.y = f2bf(sy);
            ov.z = f2bf(sz); ov.w = f2bf(sw);
            *(ushort4*)(ob + (size_t)j * D_) = ov;
        }
    }
}

// ---------------------------------------------------------------------------
// gemm: out = tmp_c . Ws_c^T + bias. 128x256 tile, BK=32, 512 thr = 8 waves
//   (2m x 4n), wave tile 64x64. Triple buffer, one barrier per K-step,
//   counted vmcnt (provable scheme, rounds 11-15).
//   NEW (round 16): LDS-transposed epilogue — per-wave 16x68-f32 scratch in
//   Bs, float4 readback, global_store_dwordx4 in 256B segments (4x the
//   previous 64B write granularity on the 64 MB out stream).
// ---------------------------------------------------------------------------
__global__ __launch_bounds__(512, 4) void gemm_k(const unsigned short* __restrict__ tmp,
                                                 const unsigned short* __restrict__ wsb,
                                                 const float* __restrict__ bs,
                                                 const float* __restrict__ Wt,
                                                 const float* __restrict__ bt,
                                                 float* __restrict__ out) {
    __shared__ unsigned short As[3][BM * BK];   // 3 x 8 KB
    __shared__ unsigned short Bs[3][BN * BK];   // 3 x 16 KB (48 KB contiguous)

    int bid = blockIdx.x;
    int c  = bid & 7;
    int t2 = bid >> 3;                 // 0..61
    int nt = t2 & 1;
    int mt = t2 >> 1;                  // 0..30
    int row0 = mt * BM;
    int o0   = nt * BN;
    int tid = threadIdx.x, lane = tid & 63, wid = tid >> 6;
    int wm = wid >> 2, wn = wid & 3;   // 2 x 4 wave grid; wave tile 64x64

    const unsigned short* Ab = tmp + (size_t)c * GM * D_;
    const unsigned short* Bb = wsb + ((size_t)c * O_ + o0) * D_;

    f32x4 acc[4][4];
#pragma unroll
    for (int m = 0; m < 4; ++m)
#pragma unroll
        for (int n = 0; n < 4; ++n)
            acc[m][n] = (f32x4){0.f, 0.f, 0.f, 0.f};

    // per stage: A 512 chunks (1/thread) + B 1024 chunks (2/thread) = 3 insts
#define STAGE(bi, kb)                                                         \
    {                                                                         \
        int qa = tid;                                                         \
        int rowa = qa >> 2, cca = qa & 3;                                     \
        int sca = cca ^ (rowa & 3);                                           \
        int ar = row0 + rowa; if (ar > GM - 1) ar = GM - 1;                   \
        async_copy16(Ab + (size_t)ar * D_ + (kb) + sca * 8,                   \
                     (unsigned short*)As[bi] + qa * 8);                       \
        _Pragma("unroll")                                                     \
        for (int h = 0; h < 2; ++h) {                                         \
            int q = h * 512 + tid;                                            \
            int row = q >> 2, cc = q & 3;                                     \
            int sc = cc ^ (row & 3);                                          \
            async_copy16(Bb + (size_t)row * D_ + (kb) + sc * 8,               \
                         (unsigned short*)Bs[bi] + q * 8);                    \
        }                                                                     \
    }

    // one K=32 slice: 4x4 MFMA per wave
#define MFMA_STEP(bi)                                                         \
    {                                                                         \
        bf16x8 af[4], bq[4];                                                  \
        _Pragma("unroll")                                                     \
        for (int m = 0; m < 4; ++m) {                                         \
            int r = wm * 64 + m * 16 + (lane & 15);                           \
            af[m] = *(const bf16x8*)&As[bi][r * BK +                          \
                    (((lane >> 4) ^ (r & 3)) << 3)];                          \
        }                                                                     \
        _Pragma("unroll")                                                     \
        for (int n = 0; n < 4; ++n) {                                         \
            int o = wn * 64 + n * 16 + (lane & 15);                           \
            bq[n] = *(const bf16x8*)&Bs[bi][o * BK +                          \
                    (((lane >> 4) ^ (o & 3)) << 3)];                          \
        }                                                                     \
        _Pragma("unroll")                                                     \
        for (int m = 0; m < 4; ++m)                                           \
            _Pragma("unroll")                                                 \
            for (int n = 0; n < 4; ++n)                                       \
                acc[m][n] = __builtin_amdgcn_mfma_f32_16x16x32_bf16(          \
                    af[m], bq[n], acc[m][n], 0, 0, 0);                        \
    }

    // ---- prologue: stage 0,1; drain both (provable); barrier ----
    STAGE(0, 0)
    STAGE(1, BK)
    asm volatile("s_waitcnt vmcnt(0)" ::: "memory");
    __builtin_amdgcn_sched_barrier(0);
    asm volatile("s_barrier" ::: "memory");

    // ---- K-loop: 16 steps, 3-buffer, ONE barrier per step ----
#pragma unroll
    for (int t = 0; t < NSTEP; ++t) {
        MFMA_STEP(t % 3)
        if (t == NSTEP - 1) break;
        asm volatile("s_waitcnt lgkmcnt(0)" ::: "memory");
        __builtin_amdgcn_sched_barrier(0);
        if (t + 2 < NSTEP) STAGE((t + 2) % 3, (t + 2) * BK)
        if (t < NSTEP - 2)
            asm volatile("s_waitcnt vmcnt(3)" ::: "memory");  // certify t+1
        else
            asm volatile("s_waitcnt vmcnt(0)" ::: "memory");  // tail
        __builtin_amdgcn_sched_barrier(0);
        asm volatile("s_barrier" ::: "memory");   // step separator
    }

    // ---- epilogue: LDS-transposed stores (256B segments) ----
    // All waves' final ds_reads must land before Bs is repurposed:
    asm volatile("s_waitcnt lgkmcnt(0)" ::: "memory");
    __builtin_amdgcn_sched_barrier(0);
    asm volatile("s_barrier" ::: "memory");

    float S = 0.f;
#pragma unroll
    for (int p = 0; p < P_; ++p) S += Wt[c * P_ + p];
    float btc = bt[c];

    // per-wave private scratch: 16 rows x 68 f32 (stride 68 -> 2-way free)
    float* scr = (float*)&Bs[0][0] + wid * (16 * 68);   // 8 x 4352B = 34 KB
    int colg = o0 + wn * 64 + (lane & 15) * 4;
    float4 bs4 = *(const float4*)&bs[c * O_ + colg];
    float4 addv;
    addv.x = bs4.x * S + btc; addv.y = bs4.y * S + btc;
    addv.z = bs4.z * S + btc; addv.w = bs4.w * S + btc;

#pragma unroll
    for (int m = 0; m < 4; ++m) {
        // scatter this m-pass (16 rows x 64 cols) into scratch
#pragma unroll
        for (int n = 0; n < 4; ++n)
#pragma unroll
            for (int i = 0; i < 4; ++i)
                scr[((lane >> 4) * 4 + i) * 68 + n * 16 + (lane & 15)] =
                    acc[m][n][i];
        // gather float4 and store 256B-contiguous per 16-lane group
        int gr0 = row0 + wm * 64 + m * 16;
#pragma unroll
        for (int rp = 0; rp < 4; ++rp) {
            int lrow = rp * 4 + (lane >> 4);
            float4 v = *(float4*)&scr[lrow * 68 + (lane & 15) * 4];
            int grow = gr0 + lrow;
            if (grow < GM) {
                float4 o4;
                o4.x = v.x + addv.x; o4.y = v.y + addv.y;
                o4.z = v.z + addv.z; o4.w = v.w + addv.w;
                *(float4*)&out[((size_t)grow * C_ + c) * O_ + colg] = o4;
            }
        }
    }
#undef STAGE
#undef MFMA_STEP
}

// ---------------------------------------------------------------------------
// Fallback (ws too small): slow but correct, no workspace.
// ---------------------------------------------------------------------------
__global__ __launch_bounds__(256) void naive_k(const float* __restrict__ inp,
                                               const float* __restrict__ Ws,
                                               const float* __restrict__ bs,
                                               const float* __restrict__ Wt,
                                               const float* __restrict__ bt,
                                               float* __restrict__ out) {
    __shared__ float tmp[D_];
    int bid = blockIdx.x;
    int c = bid & 7; int r = bid >> 3;
    int l = r % LOUT; int b = r / LOUT;
    int tid = threadIdx.x;

    for (int d = tid; d < D_; d += 256) {
        float s = 0.f;
        for (int p = 0; p < P_; ++p)
            s += Wt[c * P_ + p] * inp[((size_t)b * L_ + l + p) * D_ + d];
        tmp[d] = s;
    }
    __syncthreads();
    float S = 0.f;
    for (int p = 0; p < P_; ++p) S += Wt[c * P_ + p];
    for (int o = tid; o < O_; o += 256) {
        const float* wrow = Ws + ((size_t)c * O_ + o) * D_;
        float s = 0.f;
        for (int d = 0; d < D_; ++d) s += wrow[d] * tmp[d];
        out[(((size_t)b * LOUT + l) * C_ + c) * O_ + o] =
            s + bs[c * O_ + o] * S + bt[c];
    }
}

extern "C" void kernel_launch(void* const* d_in, const int* in_sizes, int n_in,
                              void* d_out, int out_size, void* d_ws, size_t ws_size,
                              hipStream_t stream) {
    const float* inp = (const float*)d_in[0];
    const float* Ws  = (const float*)d_in[1];
    const float* bs  = (const float*)d_in[2];
    const float* Wt  = (const float*)d_in[3];
    const float* bt  = (const float*)d_in[4];
    float* out = (float*)d_out;

    const size_t TMPB = (size_t)C_ * GM * D_ * 2;   // 31,981,568
    const size_t WSBB = (size_t)C_ * O_ * D_ * 2;   //  4,194,304

    if (ws_size >= TMPB + WSBB) {
        unsigned short* tmpb = (unsigned short*)d_ws;
        unsigned short* wsb  = (unsigned short*)((char*)d_ws + TMPB);
        prep<<<NFIRB + 2048, 256, 0, stream>>>(inp, Ws, Wt, tmpb, wsb);
        gemm_k<<<NMT * NNT * C_, 512, 0, stream>>>(tmpb, wsb, bs, Wt, bt, out);
    } else {
        naive_k<<<B_ * LOUT * C_, 256, 0, stream>>>(inp, Ws, bs, Wt, bt, out);
    }
}